// Round 5
// baseline (505.075 us; speedup 1.0000x reference)
//
#include <hip/hip_runtime.h>

#define BB 8192
#define DD 2048
#define NSLOT 7
#define NP1 (BB + 2*256)   // 8704 (256-aligned groups)
#define NP2 (BB + 4*256)   // 9216

typedef unsigned short u16;
typedef unsigned int   u32;
typedef unsigned long long u64;

typedef __bf16 bf16x8 __attribute__((ext_vector_type(8)));
typedef float  f32x4  __attribute__((ext_vector_type(4)));
typedef u16    u16x8  __attribute__((ext_vector_type(8)));

// ---- workspace layout (bytes). h1 reuses the xb region (xb dead after stage0).
#define OFF_WT   0ull
#define OFF_XB   (OFF_WT + (size_t)NSLOT*DD*DD*2)    // 58,720,256
#define OFF_H0   (OFF_XB + (size_t)BB*DD*2)          // 92,274,688
#define OFF_P1   (OFF_H0 + (size_t)BB*DD*2)          // 125,829,120
#define OFF_P2   (OFF_P1 + (size_t)NP1*4)
#define OFF_META (OFF_P2 + (size_t)NP2*4)
// meta ints: [12..14] bases1, [15..19] bases2, [20] input-is-bf16 flag

__device__ __forceinline__ u16 f2bf(float f) {
  u32 u = __float_as_uint(f);
  u32 r = (u + 0x7FFFu + ((u >> 16) & 1u)) >> 16;
  return (u16)r;
}
__device__ __forceinline__ float bf2f(u16 u) {
  return __uint_as_float(((u32)u) << 16);
}

__device__ __forceinline__ void gld16(const void* g, void* l) {
  __builtin_amdgcn_global_load_lds(
      (const __attribute__((address_space(1))) void*)g,
      (__attribute__((address_space(3))) void*)l, 16, 0, 0);
}

// ---------------- setup kernels ----------------

// Decide whether buffers are bf16-stored or fp32-stored.
__global__ void k_detect(const u16* x, int* meta) {
  __shared__ int cnt, cntz;
  if (threadIdx.x == 0) { cnt = 0; cntz = 0; }
  __syncthreads();
  u16 u = x[threadIdx.x * 17];       // odd stride mixes both parities
  int ex = (u >> 7) & 0xFF;
  int sane = (ex == 0) || (ex >= 112 && ex <= 143);
  atomicAdd(&cnt, sane);
  atomicAdd(&cntz, (u == 0) ? 1 : 0);
  __syncthreads();
  if (threadIdx.x == 0) meta[20] = (cnt >= 205 && cntz < 64) ? 1 : 0;
}

// Single-block routing: count via wave ballots, 256-align group bases,
// fill perms with ballot-prefix slot assignment.
__global__ __launch_bounds__(1024) void k_route(const int* __restrict__ pm,
                                                int* __restrict__ p1,
                                                int* __restrict__ p2,
                                                int* __restrict__ meta) {
  __shared__ int cnt[6];            // [0..1] stage1, [2..5] stage2
  __shared__ int cur[6];
  __shared__ int base1[2], base2[4];
  const int tid = threadIdx.x;
  const int lane = tid & 63;
  if (tid < 6) { cnt[tid] = 0; cur[tid] = 0; }
  __syncthreads();

  for (int i = tid; i < NP1; i += 1024) p1[i] = -1;
  for (int i = tid; i < NP2; i += 1024) p2[i] = -1;

  int myb0[8], myleaf[8];
  #pragma unroll
  for (int i = 0; i < 8; ++i) {
    int b = i * 1024 + tid;
    int b0 = pm[b*3] & 1, b1 = pm[b*3+1] & 1;
    myb0[i] = b0; myleaf[i] = b0*2 + b1;
  }
  #pragma unroll
  for (int i = 0; i < 8; ++i) {
    u64 m0 = __ballot(myb0[i] == 0);
    if (lane == 0) {
      atomicAdd(&cnt[0], __popcll(m0));
      atomicAdd(&cnt[1], 64 - __popcll(m0));
    }
    #pragma unroll
    for (int e = 0; e < 4; ++e) {
      u64 me = __ballot(myleaf[i] == e);
      if (lane == 0) atomicAdd(&cnt[2+e], __popcll(me));
    }
  }
  __syncthreads();
  if (tid == 0) {
    base1[0] = 0;
    base1[1] = (cnt[0] + 255) & ~255;
    meta[12] = 0; meta[13] = base1[1];
    meta[14] = base1[1] + ((cnt[1] + 255) & ~255);
    int b = 0;
    #pragma unroll
    for (int e = 0; e < 4; ++e) {
      base2[e] = b; meta[15+e] = b;
      b += (cnt[2+e] + 255) & ~255;
    }
    meta[19] = b;
  }
  __syncthreads();
  #pragma unroll
  for (int i = 0; i < 8; ++i) {
    int b = i * 1024 + tid;
    u64 lt = (1ull << lane) - 1ull;
    #pragma unroll
    for (int g = 0; g < 2; ++g) {
      u64 m = __ballot(myb0[i] == g);
      int pos = __popcll(m & lt);
      int wbase = 0;
      if (lane == 0 && m) wbase = atomicAdd(&cur[g], __popcll(m));
      wbase = __shfl(wbase, 0);
      if (myb0[i] == g) p1[base1[g] + wbase + pos] = b;
    }
    #pragma unroll
    for (int g = 0; g < 4; ++g) {
      u64 m = __ballot(myleaf[i] == g);
      int pos = __popcll(m & lt);
      int wbase = 0;
      if (lane == 0 && m) wbase = atomicAdd(&cur[2+g], __popcll(m));
      wbase = __shfl(wbase, 0);
      if (myleaf[i] == g) p2[base2[g] + wbase + pos] = b;
    }
  }
}

// x -> bf16 (copy if already bf16)
__global__ void k_cvtx(const void* __restrict__ x, u16* __restrict__ xb,
                       const int* __restrict__ meta) {
  int i = blockIdx.x * 256 + threadIdx.x;
  if (meta[20]) {
    ((uint4*)xb)[i] = ((const uint4*)x)[i];
  } else {
    const float4* p = (const float4*)x + (size_t)i * 2;
    float4 a = p[0], b = p[1];
    uint4 o;
    o.x = f2bf(a.x) | ((u32)f2bf(a.y) << 16);
    o.y = f2bf(a.z) | ((u32)f2bf(a.w) << 16);
    o.z = f2bf(b.x) | ((u32)f2bf(b.y) << 16);
    o.w = f2bf(b.z) | ((u32)f2bf(b.w) << 16);
    ((uint4*)xb)[i] = o;
  }
}

// transpose+convert weights into 7 slots of Wt[n][k] bf16.
__global__ void k_wt(const void* __restrict__ W0, const void* __restrict__ W1,
                     const void* __restrict__ W2, u16* __restrict__ wt,
                     const int* __restrict__ meta) {
  __shared__ u16 tile[64][66];
  int bid = blockIdx.x;
  int slot = bid >> 10;          // 1024 tiles per slot (32x32 of 64x64)
  int t = bid & 1023;
  int tr = t >> 5, tc = t & 31;
  const void* src; size_t eoff;
  if (slot == 0)      { src = W0; eoff = 0; }
  else if (slot <= 2) { src = W1; eoff = (size_t)(slot-1)*DD*DD; }
  else                { src = W2; eoff = (size_t)(slot-3)*DD*DD; }
  int r0 = tr*64, c0 = tc*64;
  int tid = threadIdx.x;
  int isbf = meta[20];
  #pragma unroll
  for (int i = 0; i < 4; ++i) {
    int idx = tid + i*256;
    int r = idx >> 4, c4 = (idx & 15) * 4;
    size_t goff = eoff + (size_t)(r0 + r)*DD + c0 + c4;
    u16 v0, v1, v2, v3;
    if (isbf) {
      ushort4 v = *(const ushort4*)((const u16*)src + goff);
      v0 = v.x; v1 = v.y; v2 = v.z; v3 = v.w;
    } else {
      float4 v = *(const float4*)((const float*)src + goff);
      v0 = f2bf(v.x); v1 = f2bf(v.y); v2 = f2bf(v.z); v3 = f2bf(v.w);
    }
    tile[r][c4+0] = v0; tile[r][c4+1] = v1;
    tile[r][c4+2] = v2; tile[r][c4+3] = v3;
  }
  __syncthreads();
  u16* dst = wt + (size_t)slot*DD*DD;
  #pragma unroll
  for (int i = 0; i < 2; ++i) {
    int idx = tid + i*256;          // 512 jobs: n = idx>>3, 16B chunk j = idx&7
    int n = idx >> 3, j = idx & 7;
    u16x8 o;
    #pragma unroll
    for (int k = 0; k < 8; ++k) o[k] = tile[j*8 + k][n];
    *(u16x8*)&dst[(size_t)(c0 + n)*DD + r0 + j*8] = o;
  }
}

// ---------------- GEMM: C = relu(A @ W + bias), expert-routed ----------------
// m201-style 8-phase port. BM=256 x BN=128, BK=64, 512 thr = 8 waves (4M x 2N,
// per-wave 64x64, acc[4][4]). K-tile = 2 phases (kk=0/1), each:
//   {8 ds_read_b128 -> stage ONE half-tile (3 gld16) -> lgkmcnt(0)+sched_bar
//    -> setprio(1) 16 MFMA setprio(0)}.
// ONE barrier per K-tile (at the vmcnt-drain/publication point) -> waves slip
// across phases, LDS-read of one wave overlaps MFMA of another (the 2-phase
// plateau killer per m233/m248).
// Half-tile = A-half 128rows x 64k (16KB) + B-half 64rows x 64k (8KB) = 24KB.
// Ring of 6 halves = 144 KiB LDS, 1 block/CU. Stage distance 2 K-tiles;
// steady vmcnt(6) (= 2 halves in flight, NEVER 0); tail 6 -> 0.
// Publication: own vmcnt drain -> s_barrier -> reads (round-1 lesson).
// Slot overwrite: slot re-staged >= 2 tiles after last read, behind barrier.
// Swizzle (128B rows): phys 16B-chunk = logical ^ (row&7).
//   store: linear gld dest + pre-swizzled global k: (tid&7)^((tid>>3)&7).
//   read:  off = 64*(kk ^ ((cl>>2)&1)) + 16*(q ^ (cl&3));  8 lanes per
//   4-bank group = 2/bank over the 8-cy transaction -> conflict-free.
#define STGH(SLOT, P, TI) do {                                               \
    const size_t ko = (size_t)(TI) * 64;                                     \
    gld16(gA##P##0 + ko, sm + (SLOT)*24576 +     0 + widoff);                \
    gld16(gA##P##1 + ko, sm + (SLOT)*24576 +  8192 + widoff);                \
    gld16(gB##P    + ko, sm + (SLOT)*24576 + 16384 + widoff);                \
  } while (0)

#define TILE(S0, S1, SS0, SS1, T, STAGE, VMN) do {                           \
  asm volatile("s_waitcnt vmcnt(" #VMN ")" ::: "memory");                    \
  __builtin_amdgcn_s_barrier();                                              \
  {                                                                          \
    const u32 sA = (ahalf ? (u32)(S1) : (u32)(S0)) * 24576u + arow;          \
    const u32 sB = (bhalf ? (u32)(S1) : (u32)(S0)) * 24576u + 16384u + brow; \
    bf16x8 a0[4], b0[4];                                                     \
    _Pragma("unroll") for (int mt = 0; mt < 4; ++mt)                         \
      a0[mt] = *(const bf16x8*)(sm + sA + mt*2048 + o0);                     \
    _Pragma("unroll") for (int nt = 0; nt < 4; ++nt)                         \
      b0[nt] = *(const bf16x8*)(sm + sB + nt*2048 + o0);                     \
    if (STAGE) STGH(SS0, 0, (T) + 2);                                        \
    asm volatile("s_waitcnt lgkmcnt(0)" ::: "memory");                       \
    __builtin_amdgcn_sched_barrier(0);                                       \
    __builtin_amdgcn_s_setprio(1);                                           \
    _Pragma("unroll") for (int mt = 0; mt < 4; ++mt)                         \
      _Pragma("unroll") for (int nt = 0; nt < 4; ++nt)                       \
        acc[mt][nt] = __builtin_amdgcn_mfma_f32_16x16x32_bf16(               \
            a0[mt], b0[nt], acc[mt][nt], 0, 0, 0);                           \
    __builtin_amdgcn_s_setprio(0);                                           \
    bf16x8 a1[4], b1[4];                                                     \
    _Pragma("unroll") for (int mt = 0; mt < 4; ++mt)                         \
      a1[mt] = *(const bf16x8*)(sm + sA + mt*2048 + o1);                     \
    _Pragma("unroll") for (int nt = 0; nt < 4; ++nt)                         \
      b1[nt] = *(const bf16x8*)(sm + sB + nt*2048 + o1);                     \
    if (STAGE) STGH(SS1, 1, (T) + 2);                                        \
    asm volatile("s_waitcnt lgkmcnt(0)" ::: "memory");                       \
    __builtin_amdgcn_sched_barrier(0);                                       \
    __builtin_amdgcn_s_setprio(1);                                           \
    _Pragma("unroll") for (int mt = 0; mt < 4; ++mt)                         \
      _Pragma("unroll") for (int nt = 0; nt < 4; ++nt)                       \
        acc[mt][nt] = __builtin_amdgcn_mfma_f32_16x16x32_bf16(               \
            a1[mt], b1[nt], acc[mt][nt], 0, 0, 0);                           \
    __builtin_amdgcn_s_setprio(0);                                           \
  }                                                                          \
} while (0)

__global__ __launch_bounds__(512, 2) void k_gemm(
    const u16* __restrict__ A, const u16* __restrict__ Wt,
    const void* __restrict__ bias, const int* __restrict__ perm,
    const int* __restrict__ bases, int nexp,
    void* __restrict__ Out, int final_out, const int* __restrict__ meta) {
  extern __shared__ __align__(16) char sm[];   // 6 * 24576 = 144 KiB ring

  const int tid  = threadIdx.x;
  const int wid  = tid >> 6;
  const int lane = tid & 63;
  const u32 widoff = (u32)wid * 1024;

  // T1: XCD-chunked bijective swizzle (nwg % 8 == 0 for 512/544/576).
  const u32 nwg = gridDim.x * gridDim.y;
  const u32 wg  = blockIdx.y * gridDim.x + blockIdx.x;
  const u32 cpx = nwg >> 3;
  const u32 swz = (wg & 7u) * cpx + (wg >> 3);
  const int m0 = (int)(swz >> 4) * 256;
  const int n0 = (int)(swz & 15u) * 128;

  int e = 0;
  if (nexp == 2)      e = (m0 >= bases[1]);
  else if (nexp == 4) e = (m0 >= bases[1]) + (m0 >= bases[2]) + (m0 >= bases[3]);
  if (perm && m0 >= bases[nexp]) return;   // fully-padded tail tile
  const u16* W = Wt + (size_t)e * DD * DD;

  // staging sources. Per half-tile: 3 gld/thread, each sweep = 512thr x 16B
  // = 8KB = 64 rows x 128B. Dest row = tid>>3, phys chunk = tid&7; source
  // logical chunk = (tid&7) ^ (row&7).
  const int sr = tid >> 3;                              // 0..63
  const int kc = ((tid & 7) ^ (sr & 7)) * 8;            // pre-swizzled k
  int arr[4];
  #pragma unroll
  for (int p = 0; p < 2; ++p)
    #pragma unroll
    for (int s = 0; s < 2; ++s) {
      int r = m0 + p * 128 + s * 64 + sr;
      if (perm) { int v = perm[r]; r = (v < 0) ? 0 : v; }
      arr[p * 2 + s] = r;
    }
  const u16* gA00 = A + (size_t)arr[0] * DD + kc;   // half0 rows  0..63
  const u16* gA01 = A + (size_t)arr[1] * DD + kc;   // half0 rows 64..127
  const u16* gA10 = A + (size_t)arr[2] * DD + kc;   // half1 rows 128..191
  const u16* gA11 = A + (size_t)arr[3] * DD + kc;   // half1 rows 192..255
  const u16* gB0  = W + (size_t)(n0 + sr) * DD + kc;       // B cols  0..63
  const u16* gB1  = W + (size_t)(n0 + 64 + sr) * DD + kc;  // B cols 64..127

  // fragment geometry: wm = wid>>1 (0..3), wn = wid&1. Wave output 64x64 at
  // rows wm*64.., cols wn*64... A-half = wm>>1, row-in-half = (wm&1)*64+..;
  // B-half = wn, row-in-half = nt*16+cl.
  const int wm = wid >> 1, wn = wid & 1;
  const int ahalf = wid >> 2;          // wm>>1
  const int bhalf = wn;
  const int q = lane >> 4, cl = lane & 15;
  const u32 arow = (u32)(((wm & 1) * 64 + cl) * 128);
  const u32 brow = (u32)(cl * 128);
  const u32 o0 = (u32)(((cl >> 2) & 1) * 64 + (q ^ (cl & 3)) * 16);
  const u32 o1 = o0 ^ 64u;

  f32x4 zero = {0.0f, 0.0f, 0.0f, 0.0f};
  f32x4 acc[4][4];
  #pragma unroll
  for (int i = 0; i < 4; ++i)
    #pragma unroll
    for (int j = 0; j < 4; ++j) acc[i][j] = zero;

  // prologue: stage halves h0..h3 into slots 0..3 (12 gld outstanding).
  STGH(0, 0, 0);
  STGH(1, 1, 0);
  STGH(2, 0, 1);
  STGH(3, 1, 1);

  // main loop: 32 K-tiles (BK=64). Tile t reads halves 2t,2t+1 (slots mod 6)
  // and stages halves 2t+4,2t+5. Ring period = 3 tiles -> 3x unrolled body.
  #pragma unroll 1
  for (int t = 0; t < 30; t += 3) {
    TILE(0, 1, 4, 5, t + 0, 1, 6);
    TILE(2, 3, 0, 1, t + 1, 1, 6);
    TILE(4, 5, 2, 3, t + 2, 1, 6);
  }
  TILE(0, 1, 0, 0, 30, 0, 6);
  TILE(2, 3, 0, 0, 31, 0, 0);

  // epilogue
  const int isbf = meta[20];
  float bv[4];
  #pragma unroll
  for (int nt = 0; nt < 4; ++nt) {
    int col = n0 + wn * 64 + nt * 16 + cl;
    bv[nt] = isbf ? bf2f(((const u16*)bias)[e * DD + col])
                  : ((const float*)bias)[e * DD + col];
  }
  #pragma unroll
  for (int mt = 0; mt < 4; ++mt) {
    int rbase = m0 + wm * 64 + mt * 16 + q * 4;
    #pragma unroll
    for (int r = 0; r < 4; ++r) {
      int row = rbase + r;
      int orow = row;
      if (perm) { orow = perm[row]; if (orow < 0) continue; }
      #pragma unroll
      for (int nt = 0; nt < 4; ++nt) {
        int col = n0 + wn * 64 + nt * 16 + cl;
        float v = acc[mt][nt][r] + bv[nt];
        v = v > 0.0f ? v : 0.0f;
        if (!final_out || isbf) ((u16*)Out)[(size_t)orow * DD + col] = f2bf(v);
        else                    ((float*)Out)[(size_t)orow * DD + col] = v;
      }
    }
  }
}

#undef TILE
#undef STGH

extern "C" void kernel_launch(void* const* d_in, const int* in_sizes, int n_in,
                              void* d_out, int out_size, void* d_ws, size_t ws_size,
                              hipStream_t stream) {
  (void)in_sizes; (void)n_in; (void)out_size; (void)ws_size;
  const void* x  = d_in[0];
  const void* W0 = d_in[1];
  const void* b0 = d_in[2];
  const void* W1 = d_in[3];
  const void* b1 = d_in[4];
  const void* W2 = d_in[5];
  const void* b2 = d_in[6];
  const int*  pm = (const int*)d_in[7];

  char* ws  = (char*)d_ws;
  u16*  wt  = (u16*)(ws + OFF_WT);
  u16*  xb  = (u16*)(ws + OFF_XB);   // also reused as h1 after stage0
  u16*  h0  = (u16*)(ws + OFF_H0);
  u16*  h1  = xb;
  int*  p1  = (int*)(ws + OFF_P1);
  int*  p2  = (int*)(ws + OFF_P2);
  int*  meta= (int*)(ws + OFF_META);

  const size_t LDSB = 6 * 24576;   // 144 KiB dynamic LDS

  hipLaunchKernelGGL(k_detect, dim3(1),  dim3(256),  0, stream, (const u16*)x, meta);
  hipLaunchKernelGGL(k_route,  dim3(1),  dim3(1024), 0, stream, pm, p1, p2, meta);
  hipLaunchKernelGGL(k_cvtx,   dim3(BB*DD/8/256), dim3(256), 0, stream, x, xb, meta);
  hipLaunchKernelGGL(k_wt,     dim3(7*1024), dim3(256), 0, stream, W0, W1, W2, wt, meta);

  // stage 0: h0 = relu(x @ W0 + b0)            grid 16 n-tiles x 32 m-tiles
  hipLaunchKernelGGL(k_gemm, dim3(16, 32), dim3(512), LDSB, stream,
                     xb, wt, b0, (const int*)nullptr, (const int*)nullptr, 1,
                     (void*)h0, 0, meta);
  // stage 1: h1 = relu(h0 @ W1[bit0] + b1[bit0]), rows grouped by bit0
  hipLaunchKernelGGL(k_gemm, dim3(16, NP1/256), dim3(512), LDSB, stream,
                     h0, wt + (size_t)1*DD*DD, b1, p1, meta + 12, 2,
                     (void*)h1, 0, meta);
  // stage 2: y = relu(h1 @ W2[leaf] + b2[leaf]), rows grouped by leaf
  hipLaunchKernelGGL(k_gemm, dim3(16, NP2/256), dim3(512), LDSB, stream,
                     h1, wt + (size_t)3*DD*DD, b2, p2, meta + 15, 4,
                     d_out, 1, meta);
}